// Round 11
// baseline (57.916 us; speedup 1.0000x reference)
//
#include <hip/hip_runtime.h>
#include <hip/hip_bf16.h>

// Fused flash-attention fwd: B=8,H=12,N=1024,D=64, fp32 in/out, bf16 MFMA.
// R20 = R16 (champion) with TWO tiles per phase: prologue loads tiles 0,1;
// each phase prefetches the next 2 tiles into the opposite 2-tile buffer set
// (LDS 64KB: K bufs 0-3, V bufs 4-7) and computes 2 tiles sequentially with
// the byte-identical R16 macros, then ONE vmcnt(0)+barrier. Sync points
// 16 -> 8. Register liveness is unchanged (S pair is dead between tiles;
// only transient DMA address regs added at phase start where pressure is
// lowest) -> no spill expected, unlike the counted-vmcnt attempts. 2 blocks/
// CU unchanged (regs ~152u AND LDS 64KB both cap at 2). Targets the ~2000
// cyc/phase sync overhead (drain + 8-wave barrier + arrival jitter) that
// the budget analysis shows dominates the 4400-cyc phase.

typedef __attribute__((ext_vector_type(8))) __bf16 bf16x8;
typedef __attribute__((ext_vector_type(4))) float f32x4;
typedef __attribute__((ext_vector_type(16))) float f32x16;
typedef __attribute__((ext_vector_type(8))) unsigned short ushort8;
typedef __attribute__((ext_vector_type(2))) int int2v;

#define N_SEQ 1024
#define D_HEAD 64
#define QBLK 128
#define KBLK 64
#define NKT 16
#define NHEADS 96
#define TILE_ELEMS 4096   // 64x64 bf16 = 8KB per tensor per tile

static __device__ __forceinline__ unsigned short f2bf(float f) {
    __bf16 h = (__bf16)f;
    return __builtin_bit_cast(unsigned short, h);
}
static __device__ __forceinline__ unsigned pkbf(float a, float b) {
    union { unsigned short h[2]; unsigned u; } w;
    w.h[0] = f2bf(a); w.h[1] = f2bf(b);
    return w.u;      // v_cvt_pk_bf16_f32
}

// ------------- prep: K and V^T -> fragment-ordered bf16 tile images ---------
__global__ __launch_bounds__(256)
void prep_kv6(const float* __restrict__ K, const float* __restrict__ V,
              unsigned short* __restrict__ Kimg, unsigned short* __restrict__ Vimg)
{
    __shared__ float vt[64][65];

    const int j  = blockIdx.x;
    const int x  = j & 7;
    const int r  = j >> 3;
    const int h  = x + 8 * (r >> 4);
    const int kt = r & 15;

    const float* Kb = K + ((size_t)h * N_SEQ + kt * KBLK) * D_HEAD;
    const float* Vb = V + ((size_t)h * N_SEQ + kt * KBLK) * D_HEAD;
    unsigned short* Kt = Kimg + ((size_t)h * NKT + kt) * TILE_ELEMS;
    unsigned short* Vt = Vimg + ((size_t)h * NKT + kt) * TILE_ELEMS;

    const int tid = threadIdx.x;
    const int o   = tid >> 6;
    const int l   = tid & 63;
    const int m   = l & 31;
    const int hi  = l >> 5;

    {
        const int kvblk = o & 1, dblk0 = o >> 1;
        #pragma unroll
        for (int rep = 0; rep < 2; ++rep) {
            const int dblk = dblk0 + rep * 2;
            const float* src = Kb + (size_t)(kvblk * 32 + m) * D_HEAD + dblk * 16 + hi * 8;
            f32x4 a0 = *(const f32x4*)src, a1 = *(const f32x4*)(src + 4);
            union { unsigned short u[8]; ushort8 v; } w;
            #pragma unroll
            for (int e = 0; e < 4; ++e) { w.u[e] = f2bf(a0[e]); w.u[4+e] = f2bf(a1[e]); }
            *(ushort8*)&Kt[(dblk * 2 + kvblk) * 512 + l * 8] = w.v;
        }
    }
    {
        const int row = tid >> 2, c = tid & 3;
        const f32x4* src = (const f32x4*)(Vb + (size_t)row * D_HEAD + c * 16);
        f32x4 b0 = src[0], b1 = src[1], b2 = src[2], b3 = src[3];
        #pragma unroll
        for (int e = 0; e < 4; ++e) {
            vt[row][c*16 +      e] = b0[e];
            vt[row][c*16 +  4 + e] = b1[e];
            vt[row][c*16 +  8 + e] = b2[e];
            vt[row][c*16 + 12 + e] = b3[e];
        }
    }
    __syncthreads();
    {
        const int dblk2 = o & 1, jv0 = o >> 1;
        #pragma unroll
        for (int rep = 0; rep < 2; ++rep) {
            const int jv = jv0 + rep * 2;
            union { unsigned short u[8]; ushort8 v; } w;
            #pragma unroll
            for (int e = 0; e < 8; ++e)
                w.u[e] = f2bf(vt[jv * 16 + hi * 8 + e][dblk2 * 32 + m]);
            *(ushort8*)&Vt[(jv * 2 + dblk2) * 512 + l * 8] = w.v;
        }
    }
}

// ------------- main attention kernel ----------------------------------------
#define GLDS16(g, lp) \
    __builtin_amdgcn_global_load_lds((const __attribute__((address_space(1))) void*)(g), \
                                     (__attribute__((address_space(3))) void*)(lp), 16, 0, 0)

__global__ __launch_bounds__(256, 3)
void attn_fwd20(const float* __restrict__ Q,
                const unsigned short* __restrict__ Kimg,
                const unsigned short* __restrict__ Vimg,
                float* __restrict__ O)
{
    // K tile bufs 0-3, V tile bufs 4-7 (64 KB). Set0 = bufs {0,1}, set1 = {2,3}.
    __shared__ unsigned short SH[8][TILE_ELEMS];

    const int tid  = threadIdx.x;
    const int wave = tid >> 6;
    const int lane = tid & 63;
    const int q32  = lane & 31;
    const int hi   = lane >> 5;

    const int j  = blockIdx.x;          // 768 blocks
    const int x  = j & 7;
    const int r  = j >> 3;
    const int bh = x + 8 * (r >> 3);    // XCD x owns 12 heads
    const int qt = r & 7;

    const float* Qb = Q + (size_t)bh * (N_SEQ * D_HEAD);
    float*       Ob = O + (size_t)bh * (N_SEQ * D_HEAD);
    const char*  KimgB = (const char*)(Kimg + (size_t)bh * NKT * TILE_ELEMS);
    const char*  VimgB = (const char*)(Vimg + (size_t)bh * NKT * TILE_ELEMS);

    const int stoff = tid * 16;

#define ISSUE_K(kt_, b_) do {                                        \
        const char* g_ = KimgB + (size_t)(kt_) * 8192;               \
        char* l_ = (char*)&SH[b_][0];                                \
        GLDS16(g_ + stoff,        l_ + stoff);                       \
        GLDS16(g_ + 4096 + stoff, l_ + 4096 + stoff);                \
    } while (0)
#define ISSUE_V(kt_, b_) do {                                        \
        const char* g_ = VimgB + (size_t)(kt_) * 8192;               \
        char* l_ = (char*)&SH[4 + (b_)][0];                          \
        GLDS16(g_ + stoff,        l_ + stoff);                       \
        GLDS16(g_ + 4096 + stoff, l_ + 4096 + stoff);                \
    } while (0)

    // prologue DMAs: tiles 0,1 -> bufs 0,1
    ISSUE_K(0, 0);
    ISSUE_V(0, 0);
    ISSUE_K(1, 1);
    ISSUE_V(1, 1);

    // ---- Q B-fragments
    const float QSCALE = 0.125f * 1.44269504088896f;
    const int qrow = qt * QBLK + wave * 32 + q32;
    bf16x8 qb[4];
    #pragma unroll
    for (int dblk = 0; dblk < 4; ++dblk) {
        const float* qp = Qb + (size_t)qrow * D_HEAD + dblk * 16 + hi * 8;
        f32x4 a = *(const f32x4*)qp, b = *(const f32x4*)(qp + 4);
        union { unsigned short u[8]; bf16x8 v; } w;
        #pragma unroll
        for (int e = 0; e < 4; ++e) {
            w.u[e]     = f2bf(a[e] * QSCALE);
            w.u[4 + e] = f2bf(b[e] * QSCALE);
        }
        qb[dblk] = w.v;
    }
    bf16x8 ones;
    {
        union { unsigned short u[8]; bf16x8 v; } w;
        #pragma unroll
        for (int e = 0; e < 8; ++e) w.u[e] = 0x3F80;
        ones = w.v;
    }

    f32x16 acc0 = {}, acc1 = {}, lacc = {};
    f32x16 SA0, SA1;

#define QK_TILE(S0_, S1_, kb_) do {                                              \
        const unsigned short* Klb_ = &SH[kb_][0];                                \
        _Pragma("unroll")                                                        \
        for (int dblk = 0; dblk < 4; ++dblk) {                                   \
            bf16x8 kf0 = *(const bf16x8*)&Klb_[(dblk * 2 + 0) * 512 + lane * 8]; \
            bf16x8 kf1 = *(const bf16x8*)&Klb_[(dblk * 2 + 1) * 512 + lane * 8]; \
            S0_ = __builtin_amdgcn_mfma_f32_32x32x16_bf16(kf0, qb[dblk], S0_, 0, 0, 0); \
            S1_ = __builtin_amdgcn_mfma_f32_32x32x16_bf16(kf1, qb[dblk], S1_, 0, 0, 0); \
        }                                                                        \
    } while (0)

#if __has_builtin(__builtin_amdgcn_permlane32_swap)
#define MK_PA(dst_, P_, G0_) do {                                              \
            unsigned x0 = pkbf(P_[4*(G0_)+0], P_[4*(G0_)+1]);                  \
            unsigned x1 = pkbf(P_[4*(G0_)+2], P_[4*(G0_)+3]);                  \
            unsigned y0 = pkbf(P_[4*(G0_)+4], P_[4*(G0_)+5]);                  \
            unsigned y1 = pkbf(P_[4*(G0_)+6], P_[4*(G0_)+7]);                  \
            int2v r0 = __builtin_amdgcn_permlane32_swap((int)x0, (int)y0, false, false); \
            int2v r1 = __builtin_amdgcn_permlane32_swap((int)x1, (int)y1, false, false); \
            union { unsigned d[4]; bf16x8 v; } u_;                             \
            u_.d[0] = (unsigned)r0[0]; u_.d[1] = (unsigned)r1[0];              \
            u_.d[2] = (unsigned)r0[1]; u_.d[3] = (unsigned)r1[1];              \
            dst_ = u_.v;                                                       \
        } while (0)
#else
#define MK_PA(dst_, P_, G0_) do {                                              \
            unsigned x0 = pkbf(P_[4*(G0_)+0], P_[4*(G0_)+1]);                  \
            unsigned x1 = pkbf(P_[4*(G0_)+2], P_[4*(G0_)+3]);                  \
            unsigned y0 = pkbf(P_[4*(G0_)+4], P_[4*(G0_)+5]);                  \
            unsigned y1 = pkbf(P_[4*(G0_)+6], P_[4*(G0_)+7]);                  \
            unsigned sx0 = __shfl_xor(x0, 32), sx1 = __shfl_xor(x1, 32);       \
            unsigned sy0 = __shfl_xor(y0, 32), sy1 = __shfl_xor(y1, 32);       \
            union { unsigned d[4]; bf16x8 v; } u_;                             \
            u_.d[0] = hi ? sy0 : x0;  u_.d[1] = hi ? sy1 : x1;                 \
            u_.d[2] = hi ? y0  : sx0; u_.d[3] = hi ? y1  : sx1;                \
            dst_ = u_.v;                                                       \
        } while (0)
#endif

// exp/pack S -> pa0..3, then PV + lacc from V buf vb_ (SH index 4+vb_)
#define SOFTMAX_PV(S0_, S1_, vb_) do {                                         \
        float p0[16], p1[16];                                                  \
        _Pragma("unroll")                                                      \
        for (int i = 0; i < 16; ++i) p0[i] = __builtin_amdgcn_exp2f(S0_[i]);   \
        _Pragma("unroll")                                                      \
        for (int i = 0; i < 16; ++i) p1[i] = __builtin_amdgcn_exp2f(S1_[i]);   \
        bf16x8 pa0, pa1, pa2, pa3;                                             \
        MK_PA(pa0, p0, 0);                                                     \
        MK_PA(pa1, p0, 2);                                                     \
        MK_PA(pa2, p1, 0);                                                     \
        MK_PA(pa3, p1, 2);                                                     \
        const unsigned short* Vtb_ = &SH[4 + (vb_)][0];                        \
        bf16x8 vf;                                                             \
        vf = *(const bf16x8*)&Vtb_[(0*2+0)*512 + lane*8];                      \
        acc0 = __builtin_amdgcn_mfma_f32_32x32x16_bf16(vf, pa0, acc0, 0, 0, 0);\
        vf = *(const bf16x8*)&Vtb_[(0*2+1)*512 + lane*8];                      \
        acc1 = __builtin_amdgcn_mfma_f32_32x32x16_bf16(vf, pa0, acc1, 0, 0, 0);\
        vf = *(const bf16x8*)&Vtb_[(1*2+0)*512 + lane*8];                      \
        acc0 = __builtin_amdgcn_mfma_f32_32x32x16_bf16(vf, pa1, acc0, 0, 0, 0);\
        vf = *(const bf16x8*)&Vtb_[(1*2+1)*512 + lane*8];                      \
        acc1 = __builtin_amdgcn_mfma_f32_32x32x16_bf16(vf, pa1, acc1, 0, 0, 0);\
        vf = *(const bf16x8*)&Vtb_[(2*2+0)*512 + lane*8];                      \
        acc0 = __builtin_amdgcn_mfma_f32_32x32x16_bf16(vf, pa2, acc0, 0, 0, 0);\
        vf = *(const bf16x8*)&Vtb_[(2*2+1)*512 + lane*8];                      \
        acc1 = __builtin_amdgcn_mfma_f32_32x32x16_bf16(vf, pa2, acc1, 0, 0, 0);\
        vf = *(const bf16x8*)&Vtb_[(3*2+0)*512 + lane*8];                      \
        acc0 = __builtin_amdgcn_mfma_f32_32x32x16_bf16(vf, pa3, acc0, 0, 0, 0);\
        vf = *(const bf16x8*)&Vtb_[(3*2+1)*512 + lane*8];                      \
        acc1 = __builtin_amdgcn_mfma_f32_32x32x16_bf16(vf, pa3, acc1, 0, 0, 0);\
        lacc = __builtin_amdgcn_mfma_f32_32x32x16_bf16(ones, pa0, lacc, 0, 0, 0); \
        lacc = __builtin_amdgcn_mfma_f32_32x32x16_bf16(ones, pa1, lacc, 0, 0, 0); \
        lacc = __builtin_amdgcn_mfma_f32_32x32x16_bf16(ones, pa2, lacc, 0, 0, 0); \
        lacc = __builtin_amdgcn_mfma_f32_32x32x16_bf16(ones, pa3, lacc, 0, 0, 0); \
    } while (0)

// one tile: QK -> softmax/PV (S pair reused; dead between tiles)
#define TILE(b_) do {                                                          \
        SA0 = (f32x16){}; SA1 = (f32x16){};                                    \
        QK_TILE(SA0, SA1, b_);                                                 \
        SOFTMAX_PV(SA0, SA1, b_);                                              \
    } while (0)

#define WAITBAR asm volatile("s_waitcnt vmcnt(0)\n\ts_barrier" ::: "memory")

    WAITBAR;                           // tiles 0,1 ready in bufs 0,1

    for (int it = 0; it < 4; ++it) {
        const int t = it * 4;
        // ---- phase A: compute tiles t,t+1 (bufs 0,1); prefetch t+2,t+3 -> bufs 2,3
        ISSUE_K(t + 2, 2);
        ISSUE_V(t + 2, 2);
        ISSUE_K(t + 3, 3);
        ISSUE_V(t + 3, 3);
        TILE(0);
        TILE(1);
        WAITBAR;                       // t+2,t+3 landed; bufs 0,1 reads done

        // ---- phase B: compute tiles t+2,t+3 (bufs 2,3); prefetch t+4,t+5 -> bufs 0,1
        if (it < 3) {
            ISSUE_K(t + 4, 0);
            ISSUE_V(t + 4, 0);
            ISSUE_K(t + 5, 1);
            ISSUE_V(t + 5, 1);
        }
        TILE(2);
        TILE(3);
        if (it < 3) WAITBAR;           // t+4,t+5 landed; bufs 2,3 reads done
    }

    // ---- epilogue: transpose O^T -> O through reused LDS, per wave
    __syncthreads();
    float* tp = (float*)&SH[0][0] + wave * 2048;
    const float inv = 1.0f / lacc[0];
    #pragma unroll
    for (int db = 0; db < 2; ++db) {
        #pragma unroll
        for (int reg = 0; reg < 16; ++reg) {
            const int d = db * 32 + (reg & 3) + 4 * hi + 8 * (reg >> 2);
            const int dwi = q32 * 64 + (((d >> 2) ^ (q32 & 15)) << 2) + (d & 3);
            tp[dwi] = (db ? acc1[reg] : acc0[reg]) * inv;
        }
    }
    asm volatile("s_waitcnt lgkmcnt(0)" ::: "memory");
    {
        const int q2 = lane >> 1, h2 = lane & 1;
        float* orow = Ob + (size_t)(qt * QBLK + wave * 32 + q2) * D_HEAD;
        #pragma unroll
        for (int c = 0; c < 8; ++c) {
            const int gd   = h2 * 8 + c;
            const int slot = gd ^ (q2 & 15);
            f32x4 v = *(const f32x4*)&tp[q2 * 64 + slot * 4];
            *(f32x4*)&orow[gd * 4] = v;
        }
    }
#undef ISSUE_K
#undef ISSUE_V
#undef QK_TILE
#undef SOFTMAX_PV
#undef TILE
#undef MK_PA
#undef WAITBAR
}

// ------------- fallback (ws too small): R4 kernel ----------------------------
typedef __attribute__((ext_vector_type(8))) unsigned short ushort8_t;
static __device__ __forceinline__ int swz(int row, int b) {
    int slot = ((b >> 4) ^ (row & 7) ^ ((row >> 3) & 7)) & 7;
    return row * 128 + (slot << 4) + (b & 15);
}

__global__ __launch_bounds__(256, 4)
void attn_fwd4(const float* __restrict__ Q, const float* __restrict__ K,
               const float* __restrict__ V, float* __restrict__ O)
{
    __shared__ unsigned short KlBuf[2][64 * 64];
    __shared__ unsigned short VtBuf[2][64 * 64];
    __shared__ unsigned short Pl[4][16 * 64];

    const int tid  = threadIdx.x;
    const int wave = tid >> 6;
    const int lane = tid & 63;
    const int lg   = lane >> 4;
    const int li   = lane & 15;

    const int j  = blockIdx.x;
    const int x  = j & 7;
    const int r  = j >> 3;
    const int bh = x + 8 * (r >> 4);
    const int qt = r & 15;

    const size_t base = (size_t)bh * (N_SEQ * D_HEAD);
    const float* Qb = Q + base;
    const float* Kb = K + base;
    const float* Vb = V + base;
    float*       Ob = O + base;

    const float QSCALE = 0.125f * 1.44269504088896f;
    bf16x8 qfrag[2];
    {
        const float* qp = Qb + (size_t)(qt * 64 + wave * 16 + li) * D_HEAD;
        #pragma unroll
        for (int ks = 0; ks < 2; ++ks) {
            const f32x4* s4 = (const f32x4*)(qp + ks * 32 + lg * 8);
            f32x4 a = s4[0], b = s4[1];
            union { unsigned short u[8]; bf16x8 v; } w;
            #pragma unroll
            for (int e = 0; e < 4; ++e) {
                w.u[e]     = f2bf(a[e] * QSCALE);
                w.u[4 + e] = f2bf(b[e] * QSCALE);
            }
            qfrag[ks] = w.v;
        }
    }

    f32x4 acc[4];
    #pragma unroll
    for (int dc = 0; dc < 4; ++dc) { f32x4 z = {0.f,0.f,0.f,0.f}; acc[dc] = z; }
    float mrun = -1e30f, lrun = 0.f;

    const int kr = tid >> 2, kq = tid & 3;
    const int vp = tid >> 3, vc = tid & 7;

    f32x4 kreg[4], vreg[4];

#define ISSUE_LOADS(kt_) do {                                                          \
        const f32x4* ks4_ = (const f32x4*)(Kb + (size_t)((kt_) * KBLK + kr) * D_HEAD + kq * 16); \
        kreg[0] = ks4_[0]; kreg[1] = ks4_[1]; kreg[2] = ks4_[2]; kreg[3] = ks4_[3];    \
        const float* r0_ = Vb + (size_t)((kt_) * KBLK + 2 * vp) * D_HEAD + vc * 8;     \
        const f32x4* v0_ = (const f32x4*)r0_;                                          \
        const f32x4* v1_ = (const f32x4*)(r0_ + D_HEAD);                               \
        vreg[0] = v0_[0]; vreg[1] = v0_[1]; vreg[2] = v1_[0]; vreg[3] = v1_[1];        \
    } while (0)

#define WRITE_LDS(bufi_) do {                                                          \
        unsigned short* Klb_ = &KlBuf[bufi_][0];                                       \
        unsigned short* Vtb_ = &VtBuf[bufi_][0];                                       \
        union { unsigned short u[8]; ushort8_t v8; } w0_, w1_;                         \
        _Pragma("unroll")                                                              \
        for (int e = 0; e < 4; ++e) {                                                  \
            w0_.u[e]   = f2bf(kreg[0][e]); w0_.u[4+e] = f2bf(kreg[1][e]);              \
            w1_.u[e]   = f2bf(kreg[2][e]); w1_.u[4+e] = f2bf(kreg[3][e]);              \
        }                                                                              \
        *(ushort8_t*)&Klb_[swz(kr, kq * 32     ) >> 1] = w0_.v8;                       \
        *(ushort8_t*)&Klb_[swz(kr, kq * 32 + 16) >> 1] = w1_.v8;                       \
        _Pragma("unroll")                                                              \
        for (int e = 0; e < 8; ++e) {                                                  \
            float lo_ = (e < 4) ? vreg[0][e] : vreg[1][e - 4];                         \
            float hi_ = (e < 4) ? vreg[2][e] : vreg[3][e - 4];                         \
            unsigned pk_ = (unsigned)f2bf(lo_) | ((unsigned)f2bf(hi_) << 16);          \
            *(unsigned*)&Vtb_[swz(vc * 8 + e, vp * 4) >> 1] = pk_;                     \
        }                                                                              \
    } while (0)

    ISSUE_LOADS(0);
    WRITE_LDS(0);
    ISSUE_LOADS(1);
    asm volatile("s_waitcnt lgkmcnt(0)\n\ts_barrier" ::: "memory");

    for (int kt = 0; kt < NKT; ++kt) {
        const unsigned short* Klb = &KlBuf[kt & 1][0];
        const unsigned short* Vtb = &VtBuf[kt & 1][0];

        f32x4 s[4];
        #pragma unroll
        for (int nc = 0; nc < 4; ++nc) { f32x4 z = {0.f,0.f,0.f,0.f}; s[nc] = z; }
        #pragma unroll
        for (int nc = 0; nc < 4; ++nc) {
            #pragma unroll
            for (int ks = 0; ks < 2; ++ks) {
                bf16x8 kf = *(const bf16x8*)&Klb[swz(nc * 16 + li, ks * 64 + lg * 16) >> 1];
                s[nc] = __builtin_amdgcn_mfma_f32_16x16x32_bf16(kf, qfrag[ks], s[nc], 0, 0, 0);
            }
        }

        float t = s[0][0];
        #pragma unroll
        for (int nc = 0; nc < 4; ++nc)
            #pragma unroll
            for (int rr = 0; rr < 4; ++rr)
                t = fmaxf(t, s[nc][rr]);
        t = fmaxf(t, __shfl_xor(t, 16));
        t = fmaxf(t, __shfl_xor(t, 32));

        if (__any(t > mrun + 8.0f)) {
            const float mn  = fmaxf(mrun, t);
            const float fac = __builtin_amdgcn_exp2f(mrun - mn);
            mrun = mn;
            lrun *= fac;
            #pragma unroll
            for (int dc = 0; dc < 4; ++dc)
                #pragma unroll
                for (int rr = 0; rr < 4; ++rr)
                    acc[dc][rr] *= fac;
        }

        float p[4][4];
        float rs = 0.f;
        #pragma unroll
        for (int nc = 0; nc < 4; ++nc)
            #pragma unroll
            for (int rr = 0; rr < 4; ++rr) {
                p[nc][rr] = __builtin_amdgcn_exp2f(s[nc][rr] - mrun);
                rs += p[nc][rr];
            }
        rs += __shfl_xor(rs, 16);
        rs += __shfl_xor(rs, 32);
        lrun += rs;

        #pragma unroll
        for (int nc = 0; nc < 4; ++nc) {
            union { unsigned short u[4]; unsigned long long ll; } w;
            #pragma unroll
            for (int rr = 0; rr < 4; ++rr) w.u[rr] = f2bf(p[nc][rr]);
            *(unsigned long long*)&Pl[wave][swz(li, nc * 32 + lg * 8) >> 1] = w.ll;
        }

        #pragma unroll
        for (int ks = 0; ks < 2; ++ks) {
            bf16x8 pa = *(const bf16x8*)&Pl[wave][swz(li, ks * 64 + lg * 16) >> 1];
            #pragma unroll
            for (int dc = 0; dc < 4; ++dc) {
                bf16x8 vf = *(const bf16x8*)&Vtb[swz(dc * 16 + li, ks * 64 + lg * 16) >> 1];
                acc[dc] = __builtin_amdgcn_mfma_f32_16x16x32_bf16(vf, pa, acc[dc], 0, 0, 0);
            }
        }

        if (kt < NKT - 1) {
            WRITE_LDS((kt + 1) & 1);
            if (kt + 2 < NKT) ISSUE_LOADS(kt + 2);
            asm volatile("s_waitcnt lgkmcnt(0)\n\ts_barrier" ::: "memory");
        }
    }

    const float inv = 1.0f / lrun;
    const int orow = qt * 64 + wave * 16 + li;
    #pragma unroll
    for (int dc = 0; dc < 4; ++dc) {
        f32x4 o;
        #pragma unroll
        for (int rr = 0; rr < 4; ++rr) o[rr] = acc[dc][rr] * inv;
        *(f32x4*)&Ob[(size_t)orow * D_HEAD + dc * 16 + lg * 4] = o;
    }
#undef ISSUE_LOADS
#undef WRITE_LDS
}

extern "C" void kernel_launch(void* const* d_in, const int* in_sizes, int n_in,
                              void* d_out, int out_size, void* d_ws, size_t ws_size,
                              hipStream_t stream) {
    const float* Q = (const float*)d_in[0];
    const float* K = (const float*)d_in[1];
    const float* V = (const float*)d_in[2];
    float* O = (float*)d_out;

    const size_t img_elems = (size_t)NHEADS * NKT * TILE_ELEMS;
    const size_t need = img_elems * 2 * 2;   // bf16, K+V = 25.2 MB

    if (ws_size >= need) {
        unsigned short* Kimg = (unsigned short*)d_ws;
        unsigned short* Vimg = Kimg + img_elems;
        prep_kv6<<<dim3(NHEADS * NKT), dim3(256), 0, stream>>>(K, V, Kimg, Vimg);
        attn_fwd20<<<dim3(NHEADS * 8), dim3(256), 0, stream>>>(Q, Kimg, Vimg, O);
    } else {
        attn_fwd4<<<dim3(NHEADS * 16), dim3(256), 0, stream>>>(Q, K, V, O);
    }
}

// Round 12
// 55.154 us; speedup vs baseline: 1.0501x; 1.0501x over previous
//
#include <hip/hip_runtime.h>
#include <hip/hip_bf16.h>

// Fused flash-attention fwd: B=8,H=12,N=1024,D=64, fp32 in/out, bf16 MFMA.
// R21 = R19/R16 verbatim (champion restore after R20's 2-tile-phase
// regression). Final ledger: single-S pair, one tile/phase, lacc/ones
// row-sum MFMAs, no setprio, launch_bounds(256,3), 32KB LDS 2x dbuf.
// Refuted levers: counted-vmcnt/rings (spill), VALU row-sum (slower at
// 2 waves/SIMD), 4-wave reg diet (structurally unreachable), fewer sync
// points (loses cross-block TLP interleave + occupancy). 44.1us attn /
// 55.3us total is this structure's stable optimum under hipcc.

typedef __attribute__((ext_vector_type(8))) __bf16 bf16x8;
typedef __attribute__((ext_vector_type(4))) float f32x4;
typedef __attribute__((ext_vector_type(16))) float f32x16;
typedef __attribute__((ext_vector_type(8))) unsigned short ushort8;
typedef __attribute__((ext_vector_type(2))) int int2v;

#define N_SEQ 1024
#define D_HEAD 64
#define QBLK 128
#define KBLK 64
#define NKT 16
#define NHEADS 96
#define TILE_ELEMS 4096   // 64x64 bf16 = 8KB per tensor per tile

static __device__ __forceinline__ unsigned short f2bf(float f) {
    __bf16 h = (__bf16)f;
    return __builtin_bit_cast(unsigned short, h);
}
static __device__ __forceinline__ unsigned pkbf(float a, float b) {
    union { unsigned short h[2]; unsigned u; } w;
    w.h[0] = f2bf(a); w.h[1] = f2bf(b);
    return w.u;      // v_cvt_pk_bf16_f32
}

// ------------- prep: K and V^T -> fragment-ordered bf16 tile images ---------
__global__ __launch_bounds__(256)
void prep_kv6(const float* __restrict__ K, const float* __restrict__ V,
              unsigned short* __restrict__ Kimg, unsigned short* __restrict__ Vimg)
{
    __shared__ float vt[64][65];

    const int j  = blockIdx.x;
    const int x  = j & 7;
    const int r  = j >> 3;
    const int h  = x + 8 * (r >> 4);
    const int kt = r & 15;

    const float* Kb = K + ((size_t)h * N_SEQ + kt * KBLK) * D_HEAD;
    const float* Vb = V + ((size_t)h * N_SEQ + kt * KBLK) * D_HEAD;
    unsigned short* Kt = Kimg + ((size_t)h * NKT + kt) * TILE_ELEMS;
    unsigned short* Vt = Vimg + ((size_t)h * NKT + kt) * TILE_ELEMS;

    const int tid = threadIdx.x;
    const int o   = tid >> 6;
    const int l   = tid & 63;
    const int m   = l & 31;
    const int hi  = l >> 5;

    {
        const int kvblk = o & 1, dblk0 = o >> 1;
        #pragma unroll
        for (int rep = 0; rep < 2; ++rep) {
            const int dblk = dblk0 + rep * 2;
            const float* src = Kb + (size_t)(kvblk * 32 + m) * D_HEAD + dblk * 16 + hi * 8;
            f32x4 a0 = *(const f32x4*)src, a1 = *(const f32x4*)(src + 4);
            union { unsigned short u[8]; ushort8 v; } w;
            #pragma unroll
            for (int e = 0; e < 4; ++e) { w.u[e] = f2bf(a0[e]); w.u[4+e] = f2bf(a1[e]); }
            *(ushort8*)&Kt[(dblk * 2 + kvblk) * 512 + l * 8] = w.v;
        }
    }
    {
        const int row = tid >> 2, c = tid & 3;
        const f32x4* src = (const f32x4*)(Vb + (size_t)row * D_HEAD + c * 16);
        f32x4 b0 = src[0], b1 = src[1], b2 = src[2], b3 = src[3];
        #pragma unroll
        for (int e = 0; e < 4; ++e) {
            vt[row][c*16 +      e] = b0[e];
            vt[row][c*16 +  4 + e] = b1[e];
            vt[row][c*16 +  8 + e] = b2[e];
            vt[row][c*16 + 12 + e] = b3[e];
        }
    }
    __syncthreads();
    {
        const int dblk2 = o & 1, jv0 = o >> 1;
        #pragma unroll
        for (int rep = 0; rep < 2; ++rep) {
            const int jv = jv0 + rep * 2;
            union { unsigned short u[8]; ushort8 v; } w;
            #pragma unroll
            for (int e = 0; e < 8; ++e)
                w.u[e] = f2bf(vt[jv * 16 + hi * 8 + e][dblk2 * 32 + m]);
            *(ushort8*)&Vt[(jv * 2 + dblk2) * 512 + l * 8] = w.v;
        }
    }
}

// ------------- main attention kernel ----------------------------------------
#define GLDS16(g, lp) \
    __builtin_amdgcn_global_load_lds((const __attribute__((address_space(1))) void*)(g), \
                                     (__attribute__((address_space(3))) void*)(lp), 16, 0, 0)

__global__ __launch_bounds__(256, 3)
void attn_fwd21(const float* __restrict__ Q,
                const unsigned short* __restrict__ Kimg,
                const unsigned short* __restrict__ Vimg,
                float* __restrict__ O)
{
    __shared__ unsigned short SH[4][TILE_ELEMS];   // [0],[1]=K bufs; [2],[3]=V bufs (32 KB)

    const int tid  = threadIdx.x;
    const int wave = tid >> 6;
    const int lane = tid & 63;
    const int q32  = lane & 31;
    const int hi   = lane >> 5;

    const int j  = blockIdx.x;          // 768 blocks
    const int x  = j & 7;
    const int r  = j >> 3;
    const int bh = x + 8 * (r >> 3);    // XCD x owns 12 heads
    const int qt = r & 7;

    const float* Qb = Q + (size_t)bh * (N_SEQ * D_HEAD);
    float*       Ob = O + (size_t)bh * (N_SEQ * D_HEAD);
    const char*  KimgB = (const char*)(Kimg + (size_t)bh * NKT * TILE_ELEMS);
    const char*  VimgB = (const char*)(Vimg + (size_t)bh * NKT * TILE_ELEMS);

    const int stoff = tid * 16;

#define ISSUE_K(kt_, b_) do {                                        \
        const char* g_ = KimgB + (size_t)(kt_) * 8192;               \
        char* l_ = (char*)&SH[b_][0];                                \
        GLDS16(g_ + stoff,        l_ + stoff);                       \
        GLDS16(g_ + 4096 + stoff, l_ + 4096 + stoff);                \
    } while (0)
#define ISSUE_V(kt_, b_) do {                                        \
        const char* g_ = VimgB + (size_t)(kt_) * 8192;               \
        char* l_ = (char*)&SH[2 + (b_)][0];                          \
        GLDS16(g_ + stoff,        l_ + stoff);                       \
        GLDS16(g_ + 4096 + stoff, l_ + 4096 + stoff);                \
    } while (0)

    // prologue DMAs: K(0)->kb0, V(0)->vb0
    ISSUE_K(0, 0);
    ISSUE_V(0, 0);

    // ---- Q B-fragments
    const float QSCALE = 0.125f * 1.44269504088896f;
    const int qrow = qt * QBLK + wave * 32 + q32;
    bf16x8 qb[4];
    #pragma unroll
    for (int dblk = 0; dblk < 4; ++dblk) {
        const float* qp = Qb + (size_t)qrow * D_HEAD + dblk * 16 + hi * 8;
        f32x4 a = *(const f32x4*)qp, b = *(const f32x4*)(qp + 4);
        union { unsigned short u[8]; bf16x8 v; } w;
        #pragma unroll
        for (int e = 0; e < 4; ++e) {
            w.u[e]     = f2bf(a[e] * QSCALE);
            w.u[4 + e] = f2bf(b[e] * QSCALE);
        }
        qb[dblk] = w.v;
    }
    bf16x8 ones;
    {
        union { unsigned short u[8]; bf16x8 v; } w;
        #pragma unroll
        for (int e = 0; e < 8; ++e) w.u[e] = 0x3F80;
        ones = w.v;
    }

    f32x16 acc0 = {}, acc1 = {}, lacc = {};
    f32x16 SA0, SA1;

#define QK_TILE(S0_, S1_, kb_) do {                                              \
        const unsigned short* Klb_ = &SH[kb_][0];                                \
        _Pragma("unroll")                                                        \
        for (int dblk = 0; dblk < 4; ++dblk) {                                   \
            bf16x8 kf0 = *(const bf16x8*)&Klb_[(dblk * 2 + 0) * 512 + lane * 8]; \
            bf16x8 kf1 = *(const bf16x8*)&Klb_[(dblk * 2 + 1) * 512 + lane * 8]; \
            S0_ = __builtin_amdgcn_mfma_f32_32x32x16_bf16(kf0, qb[dblk], S0_, 0, 0, 0); \
            S1_ = __builtin_amdgcn_mfma_f32_32x32x16_bf16(kf1, qb[dblk], S1_, 0, 0, 0); \
        }                                                                        \
    } while (0)

#if __has_builtin(__builtin_amdgcn_permlane32_swap)
#define MK_PA(dst_, P_, G0_) do {                                              \
            unsigned x0 = pkbf(P_[4*(G0_)+0], P_[4*(G0_)+1]);                  \
            unsigned x1 = pkbf(P_[4*(G0_)+2], P_[4*(G0_)+3]);                  \
            unsigned y0 = pkbf(P_[4*(G0_)+4], P_[4*(G0_)+5]);                  \
            unsigned y1 = pkbf(P_[4*(G0_)+6], P_[4*(G0_)+7]);                  \
            int2v r0 = __builtin_amdgcn_permlane32_swap((int)x0, (int)y0, false, false); \
            int2v r1 = __builtin_amdgcn_permlane32_swap((int)x1, (int)y1, false, false); \
            union { unsigned d[4]; bf16x8 v; } u_;                             \
            u_.d[0] = (unsigned)r0[0]; u_.d[1] = (unsigned)r1[0];              \
            u_.d[2] = (unsigned)r0[1]; u_.d[3] = (unsigned)r1[1];              \
            dst_ = u_.v;                                                       \
        } while (0)
#else
#define MK_PA(dst_, P_, G0_) do {                                              \
            unsigned x0 = pkbf(P_[4*(G0_)+0], P_[4*(G0_)+1]);                  \
            unsigned x1 = pkbf(P_[4*(G0_)+2], P_[4*(G0_)+3]);                  \
            unsigned y0 = pkbf(P_[4*(G0_)+4], P_[4*(G0_)+5]);                  \
            unsigned y1 = pkbf(P_[4*(G0_)+6], P_[4*(G0_)+7]);                  \
            unsigned sx0 = __shfl_xor(x0, 32), sx1 = __shfl_xor(x1, 32);       \
            unsigned sy0 = __shfl_xor(y0, 32), sy1 = __shfl_xor(y1, 32);       \
            union { unsigned d[4]; bf16x8 v; } u_;                             \
            u_.d[0] = hi ? sy0 : x0;  u_.d[1] = hi ? sy1 : x1;                 \
            u_.d[2] = hi ? y0  : sx0; u_.d[3] = hi ? y1  : sx1;                \
            dst_ = u_.v;                                                       \
        } while (0)
#endif

// exp/pack S -> pa0..3, then PV + lacc from vbuf vb_ (SH index 2+vb_)
#define SOFTMAX_PV(S0_, S1_, vb_) do {                                         \
        float p0[16], p1[16];                                                  \
        _Pragma("unroll")                                                      \
        for (int i = 0; i < 16; ++i) p0[i] = __builtin_amdgcn_exp2f(S0_[i]);   \
        _Pragma("unroll")                                                      \
        for (int i = 0; i < 16; ++i) p1[i] = __builtin_amdgcn_exp2f(S1_[i]);   \
        bf16x8 pa0, pa1, pa2, pa3;                                             \
        MK_PA(pa0, p0, 0);                                                     \
        MK_PA(pa1, p0, 2);                                                     \
        MK_PA(pa2, p1, 0);                                                     \
        MK_PA(pa3, p1, 2);                                                     \
        const unsigned short* Vtb_ = &SH[2 + (vb_)][0];                        \
        bf16x8 vf;                                                             \
        vf = *(const bf16x8*)&Vtb_[(0*2+0)*512 + lane*8];                      \
        acc0 = __builtin_amdgcn_mfma_f32_32x32x16_bf16(vf, pa0, acc0, 0, 0, 0);\
        vf = *(const bf16x8*)&Vtb_[(0*2+1)*512 + lane*8];                      \
        acc1 = __builtin_amdgcn_mfma_f32_32x32x16_bf16(vf, pa0, acc1, 0, 0, 0);\
        vf = *(const bf16x8*)&Vtb_[(1*2+0)*512 + lane*8];                      \
        acc0 = __builtin_amdgcn_mfma_f32_32x32x16_bf16(vf, pa1, acc0, 0, 0, 0);\
        vf = *(const bf16x8*)&Vtb_[(1*2+1)*512 + lane*8];                      \
        acc1 = __builtin_amdgcn_mfma_f32_32x32x16_bf16(vf, pa1, acc1, 0, 0, 0);\
        vf = *(const bf16x8*)&Vtb_[(2*2+0)*512 + lane*8];                      \
        acc0 = __builtin_amdgcn_mfma_f32_32x32x16_bf16(vf, pa2, acc0, 0, 0, 0);\
        vf = *(const bf16x8*)&Vtb_[(2*2+1)*512 + lane*8];                      \
        acc1 = __builtin_amdgcn_mfma_f32_32x32x16_bf16(vf, pa2, acc1, 0, 0, 0);\
        vf = *(const bf16x8*)&Vtb_[(3*2+0)*512 + lane*8];                      \
        acc0 = __builtin_amdgcn_mfma_f32_32x32x16_bf16(vf, pa3, acc0, 0, 0, 0);\
        vf = *(const bf16x8*)&Vtb_[(3*2+1)*512 + lane*8];                      \
        acc1 = __builtin_amdgcn_mfma_f32_32x32x16_bf16(vf, pa3, acc1, 0, 0, 0);\
        lacc = __builtin_amdgcn_mfma_f32_32x32x16_bf16(ones, pa0, lacc, 0, 0, 0); \
        lacc = __builtin_amdgcn_mfma_f32_32x32x16_bf16(ones, pa1, lacc, 0, 0, 0); \
        lacc = __builtin_amdgcn_mfma_f32_32x32x16_bf16(ones, pa2, lacc, 0, 0, 0); \
        lacc = __builtin_amdgcn_mfma_f32_32x32x16_bf16(ones, pa3, lacc, 0, 0, 0); \
    } while (0)

#define WAITBAR asm volatile("s_waitcnt vmcnt(0)\n\ts_barrier" ::: "memory")

    WAITBAR;                           // K(0), V(0) ready

    for (int it = 0; it < 8; ++it) {
        const int t = it * 2;
        // ---- phase A (tile t): reads kb0/vb0, prefetches tile t+1 into kb1/vb1
        ISSUE_K(t + 1, 1);
        ISSUE_V(t + 1, 1);
        SA0 = (f32x16){}; SA1 = (f32x16){};
        QK_TILE(SA0, SA1, 0);
        SOFTMAX_PV(SA0, SA1, 0);
        WAITBAR;                       // K/V(t+1) landed; kb0/vb0 reads done

        // ---- phase B (tile t+1): reads kb1/vb1, prefetches tile t+2 into kb0/vb0
        if (t + 2 < NKT) {
            ISSUE_K(t + 2, 0);
            ISSUE_V(t + 2, 0);
        }
        SA0 = (f32x16){}; SA1 = (f32x16){};
        QK_TILE(SA0, SA1, 1);
        SOFTMAX_PV(SA0, SA1, 1);
        if (it < 7) WAITBAR;           // K/V(t+2) landed; kb1/vb1 reads done
    }

    // ---- epilogue: transpose O^T -> O through reused LDS, per wave
    __syncthreads();
    float* tp = (float*)&SH[0][0] + wave * 2048;
    const float inv = 1.0f / lacc[0];
    #pragma unroll
    for (int db = 0; db < 2; ++db) {
        #pragma unroll
        for (int reg = 0; reg < 16; ++reg) {
            const int d = db * 32 + (reg & 3) + 4 * hi + 8 * (reg >> 2);
            const int dwi = q32 * 64 + (((d >> 2) ^ (q32 & 15)) << 2) + (d & 3);
            tp[dwi] = (db ? acc1[reg] : acc0[reg]) * inv;
        }
    }
    asm volatile("s_waitcnt lgkmcnt(0)" ::: "memory");
    {
        const int q2 = lane >> 1, h2 = lane & 1;
        float* orow = Ob + (size_t)(qt * QBLK + wave * 32 + q2) * D_HEAD;
        #pragma unroll
        for (int c = 0; c < 8; ++c) {
            const int gd   = h2 * 8 + c;
            const int slot = gd ^ (q2 & 15);
            f32x4 v = *(const f32x4*)&tp[q2 * 64 + slot * 4];
            *(f32x4*)&orow[gd * 4] = v;
        }
    }
#undef ISSUE_K
#undef ISSUE_V
#undef QK_TILE
#undef SOFTMAX_PV
#undef MK_PA
#undef WAITBAR
}

// ------------- fallback (ws too small): R4 kernel ----------------------------
typedef __attribute__((ext_vector_type(8))) unsigned short ushort8_t;
static __device__ __forceinline__ int swz(int row, int b) {
    int slot = ((b >> 4) ^ (row & 7) ^ ((row >> 3) & 7)) & 7;
    return row * 128 + (slot << 4) + (b & 15);
}

__global__ __launch_bounds__(256, 4)
void attn_fwd4(const float* __restrict__ Q, const float* __restrict__ K,
               const float* __restrict__ V, float* __restrict__ O)
{
    __shared__ unsigned short KlBuf[2][64 * 64];
    __shared__ unsigned short VtBuf[2][64 * 64];
    __shared__ unsigned short Pl[4][16 * 64];

    const int tid  = threadIdx.x;
    const int wave = tid >> 6;
    const int lane = tid & 63;
    const int lg   = lane >> 4;
    const int li   = lane & 15;

    const int j  = blockIdx.x;
    const int x  = j & 7;
    const int r  = j >> 3;
    const int bh = x + 8 * (r >> 4);
    const int qt = r & 15;

    const size_t base = (size_t)bh * (N_SEQ * D_HEAD);
    const float* Qb = Q + base;
    const float* Kb = K + base;
    const float* Vb = V + base;
    float*       Ob = O + base;

    const float QSCALE = 0.125f * 1.44269504088896f;
    bf16x8 qfrag[2];
    {
        const float* qp = Qb + (size_t)(qt * 64 + wave * 16 + li) * D_HEAD;
        #pragma unroll
        for (int ks = 0; ks < 2; ++ks) {
            const f32x4* s4 = (const f32x4*)(qp + ks * 32 + lg * 8);
            f32x4 a = s4[0], b = s4[1];
            union { unsigned short u[8]; bf16x8 v; } w;
            #pragma unroll
            for (int e = 0; e < 4; ++e) {
                w.u[e]     = f2bf(a[e] * QSCALE);
                w.u[4 + e] = f2bf(b[e] * QSCALE);
            }
            qfrag[ks] = w.v;
        }
    }

    f32x4 acc[4];
    #pragma unroll
    for (int dc = 0; dc < 4; ++dc) { f32x4 z = {0.f,0.f,0.f,0.f}; acc[dc] = z; }
    float mrun = -1e30f, lrun = 0.f;

    const int kr = tid >> 2, kq = tid & 3;
    const int vp = tid >> 3, vc = tid & 7;

    f32x4 kreg[4], vreg[4];

#define ISSUE_LOADS(kt_) do {                                                          \
        const f32x4* ks4_ = (const f32x4*)(Kb + (size_t)((kt_) * KBLK + kr) * D_HEAD + kq * 16); \
        kreg[0] = ks4_[0]; kreg[1] = ks4_[1]; kreg[2] = ks4_[2]; kreg[3] = ks4_[3];    \
        const float* r0_ = Vb + (size_t)((kt_) * KBLK + 2 * vp) * D_HEAD + vc * 8;     \
        const f32x4* v0_ = (const f32x4*)r0_;                                          \
        const f32x4* v1_ = (const f32x4*)(r0_ + D_HEAD);                               \
        vreg[0] = v0_[0]; vreg[1] = v0_[1]; vreg[2] = v1_[0]; vreg[3] = v1_[1];        \
    } while (0)

#define WRITE_LDS(bufi_) do {                                                          \
        unsigned short* Klb_ = &KlBuf[bufi_][0];                                       \
        unsigned short* Vtb_ = &VtBuf[bufi_][0];                                       \
        union { unsigned short u[8]; ushort8_t v8; } w0_, w1_;                         \
        _Pragma("unroll")                                                              \
        for (int e = 0; e < 4; ++e) {                                                  \
            w0_.u[e]   = f2bf(kreg[0][e]); w0_.u[4+e] = f2bf(kreg[1][e]);              \
            w1_.u[e]   = f2bf(kreg[2][e]); w1_.u[4+e] = f2bf(kreg[3][e]);              \
        }                                                                              \
        *(ushort8_t*)&Klb_[swz(kr, kq * 32     ) >> 1] = w0_.v8;                       \
        *(ushort8_t*)&Klb_[swz(kr, kq * 32 + 16) >> 1] = w1_.v8;                       \
        _Pragma("unroll")                                                              \
        for (int e = 0; e < 8; ++e) {                                                  \
            float lo_ = (e < 4) ? vreg[0][e] : vreg[1][e - 4];                         \
            float hi_ = (e < 4) ? vreg[2][e] : vreg[3][e - 4];                         \
            unsigned pk_ = (unsigned)f2bf(lo_) | ((unsigned)f2bf(hi_) << 16);          \
            *(unsigned*)&Vtb_[swz(vc * 8 + e, vp * 4) >> 1] = pk_;                     \
        }                                                                              \
    } while (0)

    ISSUE_LOADS(0);
    WRITE_LDS(0);
    ISSUE_LOADS(1);
    asm volatile("s_waitcnt lgkmcnt(0)\n\ts_barrier" ::: "memory");

    for (int kt = 0; kt < NKT; ++kt) {
        const unsigned short* Klb = &KlBuf[kt & 1][0];
        const unsigned short* Vtb = &VtBuf[kt & 1][0];

        f32x4 s[4];
        #pragma unroll
        for (int nc = 0; nc < 4; ++nc) { f32x4 z = {0.f,0.f,0.f,0.f}; s[nc] = z; }
        #pragma unroll
        for (int nc = 0; nc < 4; ++nc) {
            #pragma unroll
            for (int ks = 0; ks < 2; ++ks) {
                bf16x8 kf = *(const bf16x8*)&Klb[swz(nc * 16 + li, ks * 64 + lg * 16) >> 1];
                s[nc] = __builtin_amdgcn_mfma_f32_16x16x32_bf16(kf, qfrag[ks], s[nc], 0, 0, 0);
            }
        }

        float t = s[0][0];
        #pragma unroll
        for (int nc = 0; nc < 4; ++nc)
            #pragma unroll
            for (int rr = 0; rr < 4; ++rr)
                t = fmaxf(t, s[nc][rr]);
        t = fmaxf(t, __shfl_xor(t, 16));
        t = fmaxf(t, __shfl_xor(t, 32));

        if (__any(t > mrun + 8.0f)) {
            const float mn  = fmaxf(mrun, t);
            const float fac = __builtin_amdgcn_exp2f(mrun - mn);
            mrun = mn;
            lrun *= fac;
            #pragma unroll
            for (int dc = 0; dc < 4; ++dc)
                #pragma unroll
                for (int rr = 0; rr < 4; ++rr)
                    acc[dc][rr] *= fac;
        }

        float p[4][4];
        float rs = 0.f;
        #pragma unroll
        for (int nc = 0; nc < 4; ++nc)
            #pragma unroll
            for (int rr = 0; rr < 4; ++rr) {
                p[nc][rr] = __builtin_amdgcn_exp2f(s[nc][rr] - mrun);
                rs += p[nc][rr];
            }
        rs += __shfl_xor(rs, 16);
        rs += __shfl_xor(rs, 32);
        lrun += rs;

        #pragma unroll
        for (int nc = 0; nc < 4; ++nc) {
            union { unsigned short u[4]; unsigned long long ll; } w;
            #pragma unroll
            for (int rr = 0; rr < 4; ++rr) w.u[rr] = f2bf(p[nc][rr]);
            *(unsigned long long*)&Pl[wave][swz(li, nc * 32 + lg * 8) >> 1] = w.ll;
        }

        #pragma unroll
        for (int ks = 0; ks < 2; ++ks) {
            bf16x8 pa = *(const bf16x8*)&Pl[wave][swz(li, ks * 64 + lg * 16) >> 1];
            #pragma unroll
            for (int dc = 0; dc < 4; ++dc) {
                bf16x8 vf = *(const bf16x8*)&Vtb[swz(dc * 16 + li, ks * 64 + lg * 16) >> 1];
                acc[dc] = __builtin_amdgcn_mfma_f32_16x16x32_bf16(vf, pa, acc[dc], 0, 0, 0);
            }
        }

        if (kt < NKT - 1) {
            WRITE_LDS((kt + 1) & 1);
            if (kt + 2 < NKT) ISSUE_LOADS(kt + 2);
            asm volatile("s_waitcnt lgkmcnt(0)\n\ts_barrier" ::: "memory");
        }
    }

    const float inv = 1.0f / lrun;
    const int orow = qt * 64 + wave * 16 + li;
    #pragma unroll
    for (int dc = 0; dc < 4; ++dc) {
        f32x4 o;
        #pragma unroll
        for (int rr = 0; rr < 4; ++rr) o[rr] = acc[dc][rr] * inv;
        *(f32x4*)&Ob[(size_t)orow * D_HEAD + dc * 16 + lg * 4] = o;
    }
#undef ISSUE_LOADS
#undef WRITE_LDS
}

extern "C" void kernel_launch(void* const* d_in, const int* in_sizes, int n_in,
                              void* d_out, int out_size, void* d_ws, size_t ws_size,
                              hipStream_t stream) {
    const float* Q = (const float*)d_in[0];
    const float* K = (const float*)d_in[1];
    const float* V = (const float*)d_in[2];
    float* O = (float*)d_out;

    const size_t img_elems = (size_t)NHEADS * NKT * TILE_ELEMS;
    const size_t need = img_elems * 2 * 2;   // bf16, K+V = 25.2 MB

    if (ws_size >= need) {
        unsigned short* Kimg = (unsigned short*)d_ws;
        unsigned short* Vimg = Kimg + img_elems;
        prep_kv6<<<dim3(NHEADS * NKT), dim3(256), 0, stream>>>(K, V, Kimg, Vimg);
        attn_fwd21<<<dim3(NHEADS * 8), dim3(256), 0, stream>>>(Q, Kimg, Vimg, O);
    } else {
        attn_fwd4<<<dim3(NHEADS * 16), dim3(256), 0, stream>>>(Q, K, V, O);
    }
}